// Round 5
// baseline (1130.546 us; speedup 1.0000x reference)
//
#include <hip/hip_runtime.h>
#include <hip/hip_bf16.h>
#include <stdint.h>
#include <stddef.h>

#define B 4096
#define S 13
#define NG 1024     // 4*HE == 4*HD
#define MEL 20000   // 80*250
#define MELP 20096  // padded to multiple of 64 (314 x-tiles)

typedef __attribute__((ext_vector_type(8))) short bf16x8;
typedef __attribute__((ext_vector_type(4))) float f32x4;

__device__ __forceinline__ void g2l16(void* lds, const void* g) {
    __builtin_amdgcn_global_load_lds(
        (const __attribute__((address_space(1))) void*)g,
        (__attribute__((address_space(3))) void*)lds, 16, 0, 0);
}

__device__ __forceinline__ float sigm(float x) { return 1.0f / (1.0f + expf(-x)); }
__device__ __forceinline__ float b2f(unsigned short u) {
    union { float f; unsigned int i; } x; x.i = ((unsigned)u) << 16; return x.f;
}
__device__ __forceinline__ unsigned short f2bu(float f) {
    __hip_bfloat16 h = __float2bfloat16(f);
    return *reinterpret_cast<unsigned short*>(&h);
}

// 16-block group flags (device scope). Producer: barrier then +1 release.
// Consumer: spin acquire until ==16, then barrier.
__device__ __forceinline__ void gpost(int* f) {
    __syncthreads();
    if (threadIdx.x == 0)
        __hip_atomic_fetch_add(f, 1, __ATOMIC_RELEASE, __HIP_MEMORY_SCOPE_AGENT);
}
__device__ __forceinline__ void gwait(int* f) {
    if (threadIdx.x == 0) {
        while (__hip_atomic_load(f, __ATOMIC_ACQUIRE, __HIP_MEMORY_SCOPE_AGENT) < 16)
            __builtin_amdgcn_s_sleep(8);
    }
    __syncthreads();
}

// Block swizzle for gemm2: XCD-bijective (nwg%8==0) + grouped rows (G=4).
__device__ __forceinline__ void swz_decode(int wg, int nwg, int nx, int& bx, int& by) {
    const int cpx = nwg >> 3;
    wg = (wg & 7) * cpx + (wg >> 3);
    const int gsz = nx * 4;
    const int grp = wg / gsz, rem = wg % gsz;
    by = grp * 4 + (rem & 3);
    bx = rem >> 2;
}

// ---------------------------------------------------------------------------
// bf16 MFMA GEMM, 128x64 tile, BK=32, 4 waves, dbuf single-barrier (FC1/FC2).
// ---------------------------------------------------------------------------
__global__ __launch_bounds__(256) void gemm2(
    const __hip_bfloat16* __restrict__ A,
    const __hip_bfloat16* __restrict__ W,
    const float* __restrict__ bias,
    float* __restrict__ Cf,
    __hip_bfloat16* __restrict__ Cbf,
    int N, int K, int ldc, int relu, int nx)
{
    __shared__ __hip_bfloat16 As[2][128 * 32];
    __shared__ __hip_bfloat16 Bs[2][64 * 32];
    const int tid  = threadIdx.x;
    const int lane = tid & 63;
    const int wv   = tid >> 6;
    int bx, by;
    swz_decode(blockIdx.x, gridDim.x, nx, bx, by);
    const int brow = by * 128, bcol = bx * 64;
    const __hip_bfloat16* Ag = A + (size_t)brow * K;
    const __hip_bfloat16* Wg = W + (size_t)bcol * K;
    f32x4 acc[2][4] = {};
    const int sr = tid >> 2, sc = (tid & 3) * 8;
    const int l16 = lane & 15, lk = (lane >> 4) * 8;
    const int nk = K >> 5;

    #define STAGE2(buf, k0)  do {                                              \
        g2l16(&As[buf][(size_t)sr * 32 + sc],        Ag + (size_t)sr * K + (k0) + sc);        \
        g2l16(&As[buf][(size_t)(sr + 64) * 32 + sc], Ag + (size_t)(sr + 64) * K + (k0) + sc); \
        g2l16(&Bs[buf][(size_t)sr * 32 + sc],        Wg + (size_t)sr * K + (k0) + sc);        \
    } while (0)

    STAGE2(0, 0);
    __syncthreads();
    int cur = 0;
    for (int t = 0; t < nk; ++t) {
        if (t + 1 < nk) STAGE2(cur ^ 1, (t + 1) << 5);
        bf16x8 af[2], bfr[4];
        #pragma unroll
        for (int m = 0; m < 2; ++m)
            af[m] = *(const bf16x8*)&As[cur][(size_t)(wv * 32 + m * 16 + l16) * 32 + lk];
        #pragma unroll
        for (int n = 0; n < 4; ++n)
            bfr[n] = *(const bf16x8*)&Bs[cur][(size_t)(n * 16 + l16) * 32 + lk];
        #pragma unroll
        for (int m = 0; m < 2; ++m)
            #pragma unroll
            for (int n = 0; n < 4; ++n)
                acc[m][n] = __builtin_amdgcn_mfma_f32_16x16x32_bf16(af[m], bfr[n], acc[m][n], 0, 0, 0);
        __syncthreads();
        cur ^= 1;
    }

    const int r4 = (lane >> 4) * 4;
    #pragma unroll
    for (int m = 0; m < 2; ++m) {
        #pragma unroll
        for (int n = 0; n < 4; ++n) {
            const int col = bcol + n * 16 + l16;
            if (col >= N) continue;
            const float bv = bias ? bias[col] : 0.0f;
            #pragma unroll
            for (int r = 0; r < 4; ++r) {
                const int row = brow + wv * 32 + m * 16 + r4 + r;
                float v = acc[m][n][r] + bv;
                if (relu) v = v > 0.0f ? v : 0.0f;
                if (Cf)  Cf[(size_t)row * ldc + col] = v;
                if (Cbf) Cbf[(size_t)row * ldc + col] = __float2bfloat16(v);
            }
        }
    }
}

// ---------------------------------------------------------------------------
// Persistent recurrent kernel helpers
// ---------------------------------------------------------------------------
// Load W tile (64 cols x K) into LDS as [K/32] tiles of [64][32], slot-XOR
// swizzled: element (c, e) -> tile kt=e>>5, slot (e>>3 & 3) ^ ((c>>1)&3).
__device__ __forceinline__ void load_w(__hip_bfloat16* Wlds,
                                       const __hip_bfloat16* __restrict__ Wg, int K) {
    const int nch = K >> 3;            // 16B chunks per col
    const int total = 64 * nch;
    for (int gid = threadIdx.x; gid < total; gid += 512) {
        const int cc = gid / nch;
        const int kk = (gid - cc * nch) << 3;
        const bf16x8 v = *(const bf16x8*)(Wg + (size_t)cc * K + kk);
        const int kt = kk >> 5;
        const int slot = ((kk >> 3) & 3) ^ ((cc >> 1) & 3);
        *(bf16x8*)(Wlds + kt * 2048 + cc * 32 + (slot << 3)) = v;
    }
    __syncthreads();
}

// One fused GEMM(256 rows x 64 gate-cols, K) + LSTM-cell step.
// W resident in LDS (swizzled); A staged via global_load_lds with
// pre-swizzled global source (linear LDS dest); reads use matching XOR.
// c lives in creg[8] (block-local across all steps).
__device__ __forceinline__ void lstm_step(
    const __hip_bfloat16* __restrict__ Ag, int lda, int nk,
    const __hip_bfloat16* __restrict__ Wlds,
    __hip_bfloat16* __restrict__ As,           // [2 * 256*32]
    const float* __restrict__ bias, int bcol, int bx, int brow,
    float* __restrict__ creg,
    __hip_bfloat16* __restrict__ hb1, int s1,
    __hip_bfloat16* __restrict__ hb2, int s2,
    float* __restrict__ hf)
{
    const int tid = threadIdx.x;
    const int lane = tid & 63, wv = tid >> 6, l16 = lane & 15;
    const int xoff = ((((l16 >> 1) & 3) ^ (lane >> 4)) << 3);
    const int sr = tid >> 2;                       // 0..127 (rows sr, sr+128)
    const int scs = (((tid & 3) ^ ((sr >> 1) & 3)) << 3);  // swizzled src col
    const int sdst = (tid & 3) << 3;               // linear LDS dest col
    f32x4 acc[2][4] = {};

    g2l16(As + sr * 32 + sdst,         Ag + (size_t)sr * lda + scs);
    g2l16(As + (sr + 128) * 32 + sdst, Ag + (size_t)(sr + 128) * lda + scs);
    __syncthreads();
    int cur = 0;
    for (int kt = 0; kt < nk; ++kt) {
        if (kt + 1 < nk) {
            const int k0 = (kt + 1) << 5;
            __hip_bfloat16* dst = As + (cur ^ 1) * 8192;
            g2l16(dst + sr * 32 + sdst,         Ag + (size_t)sr * lda + k0 + scs);
            g2l16(dst + (sr + 128) * 32 + sdst, Ag + (size_t)(sr + 128) * lda + k0 + scs);
        }
        const __hip_bfloat16* a  = As + cur * 8192;
        const __hip_bfloat16* wt = Wlds + kt * 2048;
        bf16x8 af[2], bfr[4];
        #pragma unroll
        for (int m = 0; m < 2; ++m)
            af[m] = *(const bf16x8*)(a + (wv * 32 + m * 16 + l16) * 32 + xoff);
        #pragma unroll
        for (int n = 0; n < 4; ++n)
            bfr[n] = *(const bf16x8*)(wt + (n * 16 + l16) * 32 + xoff);
        #pragma unroll
        for (int m = 0; m < 2; ++m)
            #pragma unroll
            for (int n = 0; n < 4; ++n)
                acc[m][n] = __builtin_amdgcn_mfma_f32_16x16x32_bf16(af[m], bfr[n], acc[m][n], 0, 0, 0);
        __syncthreads();
        cur ^= 1;
    }

    const int r4 = (lane >> 4) * 4;
    const int unit = bx * 16 + l16;
    const float b0 = bias[bcol + l16];
    const float b1 = bias[bcol + 16 + l16];
    const float b2 = bias[bcol + 32 + l16];
    const float b3 = bias[bcol + 48 + l16];
    #pragma unroll
    for (int m = 0; m < 2; ++m) {
        #pragma unroll
        for (int r = 0; r < 4; ++r) {
            const int row = brow + wv * 32 + m * 16 + r4 + r;
            const float gi = acc[m][0][r] + b0;
            const float gf = acc[m][1][r] + b1;
            const float gg = acc[m][2][r] + b2;
            const float go = acc[m][3][r] + b3;
            float& cc = creg[m * 4 + r];
            const float c2 = sigm(gf) * cc + sigm(gi) * tanhf(gg);
            const float h2 = sigm(go) * tanhf(c2);
            cc = c2;
            const __hip_bfloat16 hb = __float2bfloat16(h2);
            hb1[(size_t)row * s1 + unit] = hb;
            hb2[(size_t)row * s2 + unit] = hb;
            if (hf) hf[(size_t)row * 256 + unit] = h2;
        }
    }
}

// ---------------------------------------------------------------------------
// Persistent recurrent kernel: 256 blocks (1/CU) x 512 threads.
// Group = 16 x-blocks sharing a 256-row batch slice; flag-synced, group-local.
// ---------------------------------------------------------------------------
__global__ __launch_bounds__(512, 2) void recurrent_kernel(
    __hip_bfloat16* __restrict__ xall,
    const __hip_bfloat16* __restrict__ Wenc,
    const __hip_bfloat16* __restrict__ Wdec,
    const float* __restrict__ be, const float* __restrict__ bd,
    __hip_bfloat16* __restrict__ enc_out,
    float* __restrict__ enc_score,
    float* __restrict__ h_buf,
    __hip_bfloat16* __restrict__ decA,          // [2][B][512]
    __hip_bfloat16* __restrict__ dec_out,
    const float* __restrict__ aw, const float* __restrict__ ab,
    int* __restrict__ F)
{
    __shared__ __hip_bfloat16 Wlds[16 * 2048];  // 64 KB (dec), 48 KB used (enc)
    __shared__ __hip_bfloat16 As[2 * 256 * 32]; // 32 KB
    const int tid = threadIdx.x;
    const int bid = blockIdx.x;
    const int j = bid >> 3;
    const int by = (bid & 7) * 2 + (j & 1);     // group 0..15, XCD-colocated
    const int bx = j >> 1;                      // 0..15
    const int brow = by * 256, bcol = bx * 64;
    const int lane = tid & 63, wv = tid >> 6;
    float creg[8];
    #pragma unroll
    for (int i = 0; i < 8; ++i) creg[i] = 0.0f;
    int* fEnc = F;
    int* fCtx = F + 13 * 16;
    int* fDcl = F + 26 * 16;

    // ===== encoder: 13 steps, Wenc resident =====
    load_w(Wlds, Wenc + (size_t)bcol * 384, 384);
    for (int t = 0; t < S; ++t) {
        if (t) gwait(&fEnc[(t - 1) * 16 + by]);
        __hip_bfloat16* hb1; int s1;
        float* hf = nullptr;
        if (t < S - 1) { hb1 = xall + (size_t)(t + 1) * B * 384 + 128; s1 = 384; }
        else           { hb1 = decA + 256; s1 = 512; hf = h_buf; }
        lstm_step(xall + (size_t)t * B * 384 + (size_t)brow * 384, 384, 12,
                  Wlds, As, be, bcol, bx, brow, creg,
                  hb1, s1, enc_out + (size_t)t * 256, S * 256, hf);
        gpost(&fEnc[t * 16 + by]);
    }
    gwait(&fEnc[12 * 16 + by]);

    // ===== enc_score for this block's 16 rows (16*13 dots) =====
    {
        const float a_b = ab[0];
        const f32x4 a4 = *(const f32x4*)(aw + 256 + lane * 4);
        for (int i = 0; i < 26; ++i) {
            const int idx = wv * 26 + i;           // 0..207
            const int r16 = idx / 13, s = idx - r16 * 13;
            const int r = brow + bx * 16 + r16;
            const ushort4 e4 = *(const ushort4*)(enc_out + ((size_t)r * S + s) * 256 + lane * 4);
            float sd = b2f(e4.x)*a4[0] + b2f(e4.y)*a4[1] + b2f(e4.z)*a4[2] + b2f(e4.w)*a4[3];
            #pragma unroll
            for (int off = 1; off < 64; off <<= 1) sd += __shfl_xor(sd, off);
            if (lane == 0) enc_score[(size_t)r * S + s] = sd + a_b;
        }
    }

    // ===== decoder: 13 steps, Wdec resident =====
    load_w(Wlds, Wdec + (size_t)bcol * 512, 512);
    const f32x4 awh = *(const f32x4*)(aw + lane * 4);
    for (int t = 0; t < S; ++t) {
        if (t) gwait(&fDcl[(t - 1) * 16 + by]);
        __hip_bfloat16* Ap = decA + (size_t)(t & 1) * B * 512;
        // attention: 2 rows per wave (block owns 16 rows)
        #pragma unroll
        for (int i = 0; i < 2; ++i) {
            const int r = brow + bx * 16 + wv * 2 + i;
            const f32x4 h4 = *(const f32x4*)(h_buf + (size_t)r * 256 + lane * 4);
            float sd = h4[0]*awh[0] + h4[1]*awh[1] + h4[2]*awh[2] + h4[3]*awh[3];
            #pragma unroll
            for (int off = 1; off < 64; off <<= 1) sd += __shfl_xor(sd, off);
            float sc[S], mx = -1e30f;
            #pragma unroll
            for (int s = 0; s < S; ++s) { sc[s] = sd + enc_score[(size_t)r * S + s]; mx = fmaxf(mx, sc[s]); }
            float sum = 0.0f;
            #pragma unroll
            for (int s = 0; s < S; ++s) { sc[s] = expf(sc[s] - mx); sum += sc[s]; }
            const float inv = 1.0f / sum;
            float cx0 = 0.f, cx1 = 0.f, cx2 = 0.f, cx3 = 0.f;
            #pragma unroll
            for (int s = 0; s < S; ++s) {
                const ushort4 e4 = *(const ushort4*)(enc_out + ((size_t)r * S + s) * 256 + lane * 4);
                const float w = sc[s] * inv;
                cx0 += w * b2f(e4.x); cx1 += w * b2f(e4.y);
                cx2 += w * b2f(e4.z); cx3 += w * b2f(e4.w);
            }
            ushort4 o4 = { f2bu(cx0), f2bu(cx1), f2bu(cx2), f2bu(cx3) };
            *(ushort4*)(Ap + (size_t)r * 512 + lane * 4) = o4;
        }
        gpost(&fCtx[t * 16 + by]);
        gwait(&fCtx[t * 16 + by]);
        lstm_step(Ap + (size_t)brow * 512, 512, 16,
                  Wlds, As, bd, bcol, bx, brow, creg,
                  decA + (size_t)((t + 1) & 1) * B * 512 + 256, 512,
                  dec_out + (size_t)t * 256, S * 256, h_buf);
        gpost(&fDcl[t * 16 + by]);
    }
}

// ---------------------------------------------------------------------------
// Weight prep / packing kernels (gate-permuted layouts)
// ---------------------------------------------------------------------------
__device__ __forceinline__ int unperm(int np) {
    const int u = ((np >> 6) << 4) + (np & 15);
    const int g = (np >> 4) & 3;
    return g * 256 + u;
}

__global__ void pack_enc_w(const float* __restrict__ ew_ih, const float* __restrict__ ew_hh,
                           __hip_bfloat16* __restrict__ out) {
    int idx = blockIdx.x * 256 + threadIdx.x;
    if (idx >= NG * 384) return;
    int np = idx / 384, k = idx % 384;
    int n = unperm(np);
    float v = (k < 128) ? ew_ih[n * 128 + k] : ew_hh[n * 256 + (k - 128)];
    out[idx] = __float2bfloat16(v);
}

__global__ void pack_dec_w(const float* __restrict__ dw_ih, const float* __restrict__ dw_hh,
                           __hip_bfloat16* __restrict__ out) {
    int idx = blockIdx.x * 256 + threadIdx.x;
    if (idx >= NG * 512) return;
    int np = idx / 512, k = idx % 512;
    int n = unperm(np);
    float v = (k < 256) ? dw_ih[n * 384 + 128 + k] : dw_hh[n * 256 + (k - 256)];
    out[idx] = __float2bfloat16(v);
}

__global__ void conv_bf16(const float* __restrict__ in, __hip_bfloat16* __restrict__ out,
                          long long n) {
    long long idx = (long long)blockIdx.x * 256 + threadIdx.x;
    if (idx >= n) return;
    out[idx] = __float2bfloat16(in[idx]);
}

__global__ void pack_w2(const float* __restrict__ in, __hip_bfloat16* __restrict__ out,
                        long long n_in, long long n_out) {
    long long i8 = ((long long)blockIdx.x * 256 + threadIdx.x) * 8;
    if (i8 >= n_out) return;
    union { bf16x8 v; __hip_bfloat16 e[8]; } u;
    if (i8 < n_in) {
        f32x4 a = *(const f32x4*)(in + i8);
        f32x4 b = *(const f32x4*)(in + i8 + 4);
        #pragma unroll
        for (int j = 0; j < 4; ++j) { u.e[j] = __float2bfloat16(a[j]); u.e[4 + j] = __float2bfloat16(b[j]); }
    } else {
        #pragma unroll
        for (int j = 0; j < 8; ++j) u.e[j] = __float2bfloat16(0.0f);
    }
    *(bf16x8*)(out + i8) = u.v;
}

__global__ void pad_bias_f32(const float* __restrict__ in, float* __restrict__ out,
                             int n_out, int n_in) {
    int idx = blockIdx.x * 256 + threadIdx.x;
    if (idx >= n_out) return;
    out[idx] = (idx < n_in) ? in[idx] : 0.0f;
}

__global__ void bias_prep(const float* __restrict__ eb_ih, const float* __restrict__ eb_hh,
                          const float* __restrict__ db_ih, const float* __restrict__ db_hh,
                          const float* __restrict__ dw_ih, const float* __restrict__ init_in,
                          float* __restrict__ be, float* __restrict__ bd) {
    int np = blockIdx.x * 256 + threadIdx.x;
    if (np >= NG) return;
    int n = unperm(np);
    be[np] = eb_ih[n] + eb_hh[n];
    float s = db_ih[n] + db_hh[n];
    for (int k = 0; k < 128; ++k) s += dw_ih[n * 384 + k] * init_in[k];
    bd[np] = s;
}

__global__ void embed_x(const int* __restrict__ text, const float* __restrict__ surp,
                        const float* __restrict__ emb, const float* __restrict__ sw,
                        const float* __restrict__ sb, __hip_bfloat16* __restrict__ xall) {
    int idx = blockIdx.x * 256 + threadIdx.x;
    if (idx >= B * S * 32) return;
    int jj = (idx & 31) * 4;
    int rest = idx >> 5;
    int b = rest % B;
    int s = rest / B;
    const float sp = surp[b * S + s];
    const f32x4 e4 = *(const f32x4*)(emb + (size_t)text[b * S + s] * 128 + jj);
    const f32x4 w4 = *(const f32x4*)(sw + jj);
    const f32x4 b4 = *(const f32x4*)(sb + jj);
    __hip_bfloat16* dst = xall + ((size_t)s * B + b) * 384 + jj;
    #pragma unroll
    for (int i = 0; i < 4; ++i) dst[i] = __float2bfloat16(e4[i] + sp * w4[i] + b4[i]);
}

// zero step-0 h-slot and the flag array (every call — graph replays)
__global__ void init_misc(__hip_bfloat16* __restrict__ xall, int* __restrict__ F) {
    int idx = blockIdx.x * 256 + threadIdx.x;
    if (idx < 39 * 16) F[idx] = 0;
    if (idx >= B * 256) return;
    int b = idx >> 8, jj = idx & 255;
    xall[(size_t)b * 384 + 128 + jj] = __float2bfloat16(0.0f);
}

// ---------------------------------------------------------------------------
#define CDIV(a, b) (((a) + (b) - 1) / (b))

extern "C" void kernel_launch(void* const* d_in, const int* in_sizes, int n_in,
                              void* d_out, int out_size, void* d_ws, size_t ws_size,
                              hipStream_t stream) {
    const int*   text    = (const int*)  d_in[0];
    const float* surp    = (const float*)d_in[1];
    const float* emb     = (const float*)d_in[2];
    const float* sw      = (const float*)d_in[3];
    const float* sb      = (const float*)d_in[4];
    const float* ew_ih   = (const float*)d_in[5];
    const float* ew_hh   = (const float*)d_in[6];
    const float* eb_ih   = (const float*)d_in[7];
    const float* eb_hh   = (const float*)d_in[8];
    const float* aw      = (const float*)d_in[9];
    const float* ab      = (const float*)d_in[10];
    const float* dw_ih   = (const float*)d_in[11];
    const float* dw_hh   = (const float*)d_in[12];
    const float* db_ih   = (const float*)d_in[13];
    const float* db_hh   = (const float*)d_in[14];
    const float* f1w     = (const float*)d_in[15];
    const float* f1b     = (const float*)d_in[16];
    const float* f2w     = (const float*)d_in[17];
    const float* f2b     = (const float*)d_in[18];
    const float* init_in = (const float*)d_in[19];
    float* out = (float*)d_out;

    char* p = (char*)d_ws;
    auto alloc = [&](size_t bytes) {
        void* r = (void*)p;
        p += (bytes + 255) & ~(size_t)255;
        return r;
    };
    __hip_bfloat16* Wenc      = (__hip_bfloat16*)alloc((size_t)NG * 384 * 2);
    __hip_bfloat16* Wdec      = (__hip_bfloat16*)alloc((size_t)NG * 512 * 2);
    __hip_bfloat16* W1        = (__hip_bfloat16*)alloc((size_t)NG * 3328 * 2);
    __hip_bfloat16* W2        = (__hip_bfloat16*)alloc((size_t)MELP * 1024 * 2);
    float*          f2bp      = (float*)alloc((size_t)MELP * 4);
    float*          be        = (float*)alloc((size_t)NG * 4);
    float*          bd        = (float*)alloc((size_t)NG * 4);
    __hip_bfloat16* xall      = (__hip_bfloat16*)alloc((size_t)S * B * 384 * 2);
    __hip_bfloat16* enc_out   = (__hip_bfloat16*)alloc((size_t)B * S * 256 * 2);
    float*          enc_score = (float*)alloc((size_t)B * S * 4);
    float*          h_buf     = (float*)alloc((size_t)B * 256 * 4);
    __hip_bfloat16* decA      = (__hip_bfloat16*)alloc((size_t)2 * B * 512 * 2);
    __hip_bfloat16* dec_out   = (__hip_bfloat16*)alloc((size_t)B * 3328 * 2);
    __hip_bfloat16* hfc       = (__hip_bfloat16*)alloc((size_t)B * 1024 * 2);
    int*            F         = (int*)alloc(4096);
    (void)ws_size; (void)in_sizes; (void)n_in; (void)out_size;

    // --- weight prep ---
    pack_enc_w<<<CDIV(NG * 384, 256), 256, 0, stream>>>(ew_ih, ew_hh, Wenc);
    pack_dec_w<<<CDIV(NG * 512, 256), 256, 0, stream>>>(dw_ih, dw_hh, Wdec);
    conv_bf16<<<CDIV(NG * 3328, 256), 256, 0, stream>>>(f1w, W1, (long long)NG * 3328);
    pack_w2<<<CDIV(MELP * 1024 / 8, 256), 256, 0, stream>>>(
        f2w, W2, (long long)MEL * 1024, (long long)MELP * 1024);
    pad_bias_f32<<<CDIV(MELP, 256), 256, 0, stream>>>(f2b, f2bp, MELP, MEL);
    bias_prep<<<CDIV(NG, 256), 256, 0, stream>>>(eb_ih, eb_hh, db_ih, db_hh, dw_ih, init_in, be, bd);

    // --- inputs ---
    embed_x<<<CDIV(B * S * 32, 256), 256, 0, stream>>>(text, surp, emb, sw, sb, xall);
    init_misc<<<CDIV(B * 256, 256), 256, 0, stream>>>(xall, F);

    // --- persistent recurrent section (encoder + attention + decoder) ---
    recurrent_kernel<<<256, 512, 0, stream>>>(
        xall, Wenc, Wdec, be, bd, enc_out, enc_score, h_buf, decA, dec_out, aw, ab, F);

    // --- FC1: relu(dec_out @ f1w.T + f1b) -> bf16 hfc ---
    gemm2<<<(NG / 64) * (B / 128), 256, 0, stream>>>(
        dec_out, W1, f1b, (float*)nullptr, hfc, NG, 3328, NG, 1, NG / 64);

    // --- FC2: hfc @ f2w.T + f2b -> out (fp32) ---
    gemm2<<<(MELP / 64) * (B / 128), 256, 0, stream>>>(
        hfc, W2, f2bp, out, (__hip_bfloat16*)nullptr, MEL, 1024, MEL, 0, MELP / 64);
}

// Round 6
// 786.885 us; speedup vs baseline: 1.4367x; 1.4367x over previous
//
#include <hip/hip_runtime.h>
#include <hip/hip_bf16.h>
#include <stdint.h>
#include <stddef.h>

#define B 4096
#define S 13
#define NG 1024     // 4*HE == 4*HD
#define MEL 20000   // 80*250
#define MELP 20224  // padded to multiple of 256 (79 col-tiles for gemm256)

typedef __attribute__((ext_vector_type(8))) short bf16x8;
typedef __attribute__((ext_vector_type(4))) float f32x4;

__device__ __forceinline__ void g2l16(void* lds, const void* g) {
    __builtin_amdgcn_global_load_lds(
        (const __attribute__((address_space(1))) void*)g,
        (__attribute__((address_space(3))) void*)lds, 16, 0, 0);
}

__device__ __forceinline__ float sigm(float x) { return 1.0f / (1.0f + expf(-x)); }
__device__ __forceinline__ float b2f(unsigned short u) {
    union { float f; unsigned int i; } x; x.i = ((unsigned)u) << 16; return x.f;
}
__device__ __forceinline__ unsigned short f2bu(float f) {
    __hip_bfloat16 h = __float2bfloat16(f);
    return *reinterpret_cast<unsigned short*>(&h);
}

// Block swizzle: XCD-bijective (nwg%8==0) + grouped rows (G rows/group).
__device__ __forceinline__ void swz_decode(int wg, int nwg, int nx, int& bx, int& by) {
    const int cpx = nwg >> 3;
    wg = (wg & 7) * cpx + (wg >> 3);
    const int gsz = nx * 4;                    // G = 4
    const int grp = wg / gsz, rem = wg % gsz;
    by = grp * 4 + (rem & 3);
    bx = rem >> 2;
}

// ---------------------------------------------------------------------------
// bf16 MFMA GEMM, 128x64 tile, BK=32, 4 waves, dbuf single-barrier (FC1).
// ---------------------------------------------------------------------------
__global__ __launch_bounds__(256) void gemm2(
    const __hip_bfloat16* __restrict__ A,
    const __hip_bfloat16* __restrict__ W,
    const float* __restrict__ bias,
    float* __restrict__ Cf,
    __hip_bfloat16* __restrict__ Cbf,
    int N, int K, int ldc, int relu, int nx)
{
    __shared__ __hip_bfloat16 As[2][128 * 32];
    __shared__ __hip_bfloat16 Bs[2][64 * 32];
    const int tid  = threadIdx.x;
    const int lane = tid & 63;
    const int wv   = tid >> 6;
    int bx, by;
    swz_decode(blockIdx.x, gridDim.x, nx, bx, by);
    const int brow = by * 128, bcol = bx * 64;
    const __hip_bfloat16* Ag = A + (size_t)brow * K;
    const __hip_bfloat16* Wg = W + (size_t)bcol * K;
    f32x4 acc[2][4] = {};
    const int sr = tid >> 2, sc = (tid & 3) * 8;
    const int l16 = lane & 15, lk = (lane >> 4) * 8;
    const int nk = K >> 5;

    #define STAGE2(buf, k0)  do {                                              \
        g2l16(&As[buf][(size_t)sr * 32 + sc],        Ag + (size_t)sr * K + (k0) + sc);        \
        g2l16(&As[buf][(size_t)(sr + 64) * 32 + sc], Ag + (size_t)(sr + 64) * K + (k0) + sc); \
        g2l16(&Bs[buf][(size_t)sr * 32 + sc],        Wg + (size_t)sr * K + (k0) + sc);        \
    } while (0)

    STAGE2(0, 0);
    __syncthreads();
    int cur = 0;
    for (int t = 0; t < nk; ++t) {
        if (t + 1 < nk) STAGE2(cur ^ 1, (t + 1) << 5);
        bf16x8 af[2], bfr[4];
        #pragma unroll
        for (int m = 0; m < 2; ++m)
            af[m] = *(const bf16x8*)&As[cur][(size_t)(wv * 32 + m * 16 + l16) * 32 + lk];
        #pragma unroll
        for (int n = 0; n < 4; ++n)
            bfr[n] = *(const bf16x8*)&Bs[cur][(size_t)(n * 16 + l16) * 32 + lk];
        #pragma unroll
        for (int m = 0; m < 2; ++m)
            #pragma unroll
            for (int n = 0; n < 4; ++n)
                acc[m][n] = __builtin_amdgcn_mfma_f32_16x16x32_bf16(af[m], bfr[n], acc[m][n], 0, 0, 0);
        __syncthreads();
        cur ^= 1;
    }

    const int r4 = (lane >> 4) * 4;
    #pragma unroll
    for (int m = 0; m < 2; ++m) {
        #pragma unroll
        for (int n = 0; n < 4; ++n) {
            const int col = bcol + n * 16 + l16;
            if (col >= N) continue;
            const float bv = bias ? bias[col] : 0.0f;
            #pragma unroll
            for (int r = 0; r < 4; ++r) {
                const int row = brow + wv * 32 + m * 16 + r4 + r;
                float v = acc[m][n][r] + bv;
                if (relu) v = v > 0.0f ? v : 0.0f;
                if (Cf)  Cf[(size_t)row * ldc + col] = v;
                if (Cbf) Cbf[(size_t)row * ldc + col] = __float2bfloat16(v);
            }
        }
    }
}

// ---------------------------------------------------------------------------
// 256x256 multi-phase counted-vmcnt GEMM (FC2): BK=32, 8 waves (2Mx4N),
// 3-buffer LDS rotation (96 KB), slot-XOR swizzle (T2), setprio (T5),
// vmcnt(4) per K-tile (T3+T4). C = A[M,K] @ W[N,K]^T + bias, fp32 out.
// Race-freedom: compute tile t from buf t%3; stage tile t+2 into buf
// (t+2)%3 == buf((t-1)%3), freed at the barrier that ended tile t-1.
// ---------------------------------------------------------------------------
__global__ __launch_bounds__(512, 2) void gemm256(
    const __hip_bfloat16* __restrict__ A,
    const __hip_bfloat16* __restrict__ W,
    const float* __restrict__ bias,
    float* __restrict__ Cf,
    int N, int K, int ldc, int nx)
{
    __shared__ __hip_bfloat16 As[3][256 * 32];
    __shared__ __hip_bfloat16 Bs[3][256 * 32];
    const int tid  = threadIdx.x;
    const int lane = tid & 63;
    const int wv = tid >> 6, wr = wv >> 2, wc = wv & 3;
    const int l16 = lane & 15;
    int bx, by;
    {   // XCD-bijective, G=2 rows/group (nwg = 8 * nx * 2 exactly)
        int wg = blockIdx.x; const int nwg = gridDim.x;
        const int cpx = nwg >> 3;
        wg = (wg & 7) * cpx + (wg >> 3);
        const int gsz = nx * 2;
        const int grp = wg / gsz, rem = wg % gsz;
        by = grp * 2 + (rem & 1);
        bx = rem >> 1;
    }
    const int brow = by * 256, bcol = bx * 256;
    const __hip_bfloat16* Ag = A + (size_t)brow * K;
    const __hip_bfloat16* Wg = W + (size_t)bcol * K;
    // staging: thread -> (row = tid>>2, slot = tid&3); linear LDS dest,
    // pre-swizzled global source chunk c = slot ^ ((row>>1)&3)
    const int sr = tid >> 2;
    const int sc = (((tid & 3) ^ ((tid >> 3) & 3)) << 3);
    const int sd = tid * 8;
    // read-side swizzled slot (independent of m/n since 16 % 4 == 0):
    const int sl = (((lane >> 4) ^ ((l16 >> 1) & 3)) << 3);
    f32x4 acc[8][4] = {};
    const int nk = K >> 5;

    #define STG_A(buf, k0) do { \
        g2l16(&As[buf][sd],        Ag + (size_t)sr * K + (k0) + sc);         \
        g2l16(&As[buf][4096 + sd], Ag + (size_t)(sr + 128) * K + (k0) + sc); } while (0)
    #define STG_B(buf, k0) do { \
        g2l16(&Bs[buf][sd],        Wg + (size_t)sr * K + (k0) + sc);         \
        g2l16(&Bs[buf][4096 + sd], Wg + (size_t)(sr + 128) * K + (k0) + sc); } while (0)
    #define BAR() do { asm volatile("" ::: "memory"); \
        __builtin_amdgcn_s_barrier(); \
        __builtin_amdgcn_sched_barrier(0); } while (0)

    // Two phases per K-tile: P0 = m0..3 x n0..3 (reads a0-3, b0-3, stages A
    // of t+2); P1 = m4..7 x n0..3 (reads a4-7, reuses b, stages B of t+2).
    #define TILE(cur, stg, k2, DO_STG) do {                                    \
        const __hip_bfloat16* Ab = As[cur];                                    \
        const __hip_bfloat16* Bb = Bs[cur];                                    \
        bf16x8 bfr[4], af[4];                                                  \
        _Pragma("unroll") for (int n = 0; n < 4; ++n)                          \
            bfr[n] = *(const bf16x8*)(Bb + (wc * 64 + n * 16 + l16) * 32 + sl);\
        _Pragma("unroll") for (int m = 0; m < 4; ++m)                          \
            af[m] = *(const bf16x8*)(Ab + (wr * 128 + m * 16 + l16) * 32 + sl);\
        if (DO_STG) STG_A(stg, k2);                                            \
        BAR();                                                                 \
        __builtin_amdgcn_s_setprio(1);                                         \
        _Pragma("unroll") for (int m = 0; m < 4; ++m)                          \
            _Pragma("unroll") for (int n = 0; n < 4; ++n)                      \
                acc[m][n] = __builtin_amdgcn_mfma_f32_16x16x32_bf16(           \
                    af[m], bfr[n], acc[m][n], 0, 0, 0);                        \
        __builtin_amdgcn_s_setprio(0);                                         \
        BAR();                                                                 \
        _Pragma("unroll") for (int m = 0; m < 4; ++m)                          \
            af[m] = *(const bf16x8*)(Ab + (wr * 128 + (m + 4) * 16 + l16) * 32 + sl); \
        if (DO_STG) STG_B(stg, k2);                                            \
        BAR();                                                                 \
        __builtin_amdgcn_s_setprio(1);                                         \
        _Pragma("unroll") for (int m = 0; m < 4; ++m)                          \
            _Pragma("unroll") for (int n = 0; n < 4; ++n)                      \
                acc[m + 4][n] = __builtin_amdgcn_mfma_f32_16x16x32_bf16(       \
                    af[m], bfr[n], acc[m + 4][n], 0, 0, 0);                    \
        __builtin_amdgcn_s_setprio(0);                                         \
    } while (0)

    // prologue: tiles 0,1 in flight; wait tile0 (4 own loads), keep tile1
    STG_A(0, 0);  STG_B(0, 0);
    STG_A(1, 32); STG_B(1, 32);
    asm volatile("s_waitcnt vmcnt(4)" ::: "memory");
    BAR();
    int cur = 0;
    for (int t = 0; t < nk - 2; ++t) {
        const int stg = cur >= 1 ? cur - 1 : 2;     // (cur+2)%3
        TILE(cur, stg, (t + 2) << 5, true);
        asm volatile("s_waitcnt vmcnt(4)" ::: "memory");   // tile t+1 landed
        BAR();
        cur = cur == 2 ? 0 : cur + 1;
    }
    TILE(cur, 0, 0, false);                          // t = nk-2 (no stage)
    asm volatile("s_waitcnt vmcnt(0)" ::: "memory"); // tile nk-1 landed
    BAR();
    cur = cur == 2 ? 0 : cur + 1;
    TILE(cur, 0, 0, false);                          // t = nk-1

    const int r4 = (lane >> 4) * 4;
    #pragma unroll
    for (int m = 0; m < 8; ++m) {
        #pragma unroll
        for (int n = 0; n < 4; ++n) {
            const int col = bcol + wc * 64 + n * 16 + l16;
            if (col >= N) continue;
            const float bv = bias[col];
            #pragma unroll
            for (int r = 0; r < 4; ++r) {
                const int row = brow + wr * 128 + m * 16 + r4 + r;
                Cf[(size_t)row * ldc + col] = acc[m][n][r] + bv;
            }
        }
    }
}

// ---------------------------------------------------------------------------
// Fused GEMM + LSTM cell, 128x64 dbuf structure. Weights gate-permuted:
//   n = g*256+u -> n' = (u>>4)*64 + g*16 + (u&15)
// ---------------------------------------------------------------------------
__global__ __launch_bounds__(256) void gemm_lstm(
    const __hip_bfloat16* __restrict__ A,
    const __hip_bfloat16* __restrict__ W,
    const float* __restrict__ bias,
    float* __restrict__ c,
    float* __restrict__ hf,
    __hip_bfloat16* __restrict__ hb1, int s1,
    __hip_bfloat16* __restrict__ hb2, int s2,
    int K)
{
    __shared__ __hip_bfloat16 As[2][128 * 32];
    __shared__ __hip_bfloat16 Bs[2][64 * 32];
    const int tid  = threadIdx.x;
    const int lane = tid & 63;
    const int wv   = tid >> 6;
    int bx, by;
    swz_decode(blockIdx.x, gridDim.x, 16, bx, by);
    const int brow = by * 128, bcol = bx * 64;
    const __hip_bfloat16* Ag = A + (size_t)brow * K;
    const __hip_bfloat16* Wg = W + (size_t)bcol * K;
    f32x4 acc[2][4] = {};
    const int sr = tid >> 2, sc = (tid & 3) * 8;
    const int l16 = lane & 15, lk = (lane >> 4) * 8;
    const int nk = K >> 5;

    STAGE2(0, 0);
    __syncthreads();
    int cur = 0;
    for (int t = 0; t < nk; ++t) {
        if (t + 1 < nk) STAGE2(cur ^ 1, (t + 1) << 5);
        bf16x8 af[2], bfr[4];
        #pragma unroll
        for (int m = 0; m < 2; ++m)
            af[m] = *(const bf16x8*)&As[cur][(size_t)(wv * 32 + m * 16 + l16) * 32 + lk];
        #pragma unroll
        for (int n = 0; n < 4; ++n)
            bfr[n] = *(const bf16x8*)&Bs[cur][(size_t)(n * 16 + l16) * 32 + lk];
        #pragma unroll
        for (int m = 0; m < 2; ++m)
            #pragma unroll
            for (int n = 0; n < 4; ++n)
                acc[m][n] = __builtin_amdgcn_mfma_f32_16x16x32_bf16(af[m], bfr[n], acc[m][n], 0, 0, 0);
        __syncthreads();
        cur ^= 1;
    }

    const int r4 = (lane >> 4) * 4;
    const int unit = bx * 16 + l16;
    const float b0 = bias[bcol + l16];
    const float b1 = bias[bcol + 16 + l16];
    const float b2 = bias[bcol + 32 + l16];
    const float b3 = bias[bcol + 48 + l16];
    #pragma unroll
    for (int m = 0; m < 2; ++m) {
        #pragma unroll
        for (int r = 0; r < 4; ++r) {
            const int row = brow + wv * 32 + m * 16 + r4 + r;
            const float gi = acc[m][0][r] + b0;
            const float gf = acc[m][1][r] + b1;
            const float gg = acc[m][2][r] + b2;
            const float go = acc[m][3][r] + b3;
            const size_t ci = (size_t)row * 256 + unit;
            const float c2 = sigm(gf) * c[ci] + sigm(gi) * tanhf(gg);
            const float h2 = sigm(go) * tanhf(c2);
            c[ci] = c2;
            if (hf) hf[ci] = h2;
            const __hip_bfloat16 hb = __float2bfloat16(h2);
            hb1[(size_t)row * s1 + unit] = hb;
            if (hb2) hb2[(size_t)row * s2 + unit] = hb;
        }
    }
}

// ---------------------------------------------------------------------------
// Weight prep / packing kernels (gate-permuted layouts)
// ---------------------------------------------------------------------------
__device__ __forceinline__ int unperm(int np) {
    const int u = ((np >> 6) << 4) + (np & 15);
    const int g = (np >> 4) & 3;
    return g * 256 + u;
}

__global__ void pack_enc_w(const float* __restrict__ ew_ih, const float* __restrict__ ew_hh,
                           __hip_bfloat16* __restrict__ out) {
    int idx = blockIdx.x * 256 + threadIdx.x;
    if (idx >= NG * 384) return;
    int np = idx / 384, k = idx % 384;
    int n = unperm(np);
    float v = (k < 128) ? ew_ih[n * 128 + k] : ew_hh[n * 256 + (k - 128)];
    out[idx] = __float2bfloat16(v);
}

__global__ void pack_dec_w(const float* __restrict__ dw_ih, const float* __restrict__ dw_hh,
                           __hip_bfloat16* __restrict__ out) {
    int idx = blockIdx.x * 256 + threadIdx.x;
    if (idx >= NG * 512) return;
    int np = idx / 512, k = idx % 512;
    int n = unperm(np);
    float v = (k < 256) ? dw_ih[n * 384 + 128 + k] : dw_hh[n * 256 + (k - 256)];
    out[idx] = __float2bfloat16(v);
}

__global__ void conv_bf16(const float* __restrict__ in, __hip_bfloat16* __restrict__ out,
                          long long n) {
    long long idx = (long long)blockIdx.x * 256 + threadIdx.x;
    if (idx >= n) return;
    out[idx] = __float2bfloat16(in[idx]);
}

__global__ void pack_w2(const float* __restrict__ in, __hip_bfloat16* __restrict__ out,
                        long long n_in, long long n_out) {
    long long i8 = ((long long)blockIdx.x * 256 + threadIdx.x) * 8;
    if (i8 >= n_out) return;
    union { bf16x8 v; __hip_bfloat16 e[8]; } u;
    if (i8 < n_in) {
        f32x4 a = *(const f32x4*)(in + i8);
        f32x4 b = *(const f32x4*)(in + i8 + 4);
        #pragma unroll
        for (int j = 0; j < 4; ++j) { u.e[j] = __float2bfloat16(a[j]); u.e[4 + j] = __float2bfloat16(b[j]); }
    } else {
        #pragma unroll
        for (int j = 0; j < 8; ++j) u.e[j] = __float2bfloat16(0.0f);
    }
    *(bf16x8*)(out + i8) = u.v;
}

__global__ void pad_bias_f32(const float* __restrict__ in, float* __restrict__ out,
                             int n_out, int n_in) {
    int idx = blockIdx.x * 256 + threadIdx.x;
    if (idx >= n_out) return;
    out[idx] = (idx < n_in) ? in[idx] : 0.0f;
}

__global__ void bias_prep(const float* __restrict__ eb_ih, const float* __restrict__ eb_hh,
                          const float* __restrict__ db_ih, const float* __restrict__ db_hh,
                          const float* __restrict__ dw_ih, const float* __restrict__ init_in,
                          float* __restrict__ be, float* __restrict__ bd) {
    int np = blockIdx.x * 256 + threadIdx.x;
    if (np >= NG) return;
    int n = unperm(np);
    be[np] = eb_ih[n] + eb_hh[n];
    float s = db_ih[n] + db_hh[n];
    for (int k = 0; k < 128; ++k) s += dw_ih[n * 384 + k] * init_in[k];
    bd[np] = s;
}

__global__ void embed_x(const int* __restrict__ text, const float* __restrict__ surp,
                        const float* __restrict__ emb, const float* __restrict__ sw,
                        const float* __restrict__ sb, __hip_bfloat16* __restrict__ xall) {
    int idx = blockIdx.x * 256 + threadIdx.x;
    if (idx >= B * S * 32) return;
    int jj = (idx & 31) * 4;
    int rest = idx >> 5;
    int b = rest % B;
    int s = rest / B;
    const float sp = surp[b * S + s];
    const f32x4 e4 = *(const f32x4*)(emb + (size_t)text[b * S + s] * 128 + jj);
    const f32x4 w4 = *(const f32x4*)(sw + jj);
    const f32x4 b4 = *(const f32x4*)(sb + jj);
    __hip_bfloat16* dst = xall + ((size_t)s * B + b) * 384 + jj;
    #pragma unroll
    for (int i = 0; i < 4; ++i) dst[i] = __float2bfloat16(e4[i] + sp * w4[i] + b4[i]);
}

__global__ void init_zero(float* __restrict__ c, __hip_bfloat16* __restrict__ x0h) {
    int idx = blockIdx.x * 256 + threadIdx.x;
    if (idx >= B * 256) return;
    c[idx] = 0.0f;
    int b = idx >> 8, jj = idx & 255;
    x0h[(size_t)b * 384 + 128 + jj] = __float2bfloat16(0.0f);
}

__global__ void enc_score_kernel(const __hip_bfloat16* __restrict__ enc_out,
                                 const float* __restrict__ aw, const float* __restrict__ ab,
                                 float* __restrict__ enc_score) {
    int gw = (blockIdx.x * 256 + threadIdx.x) >> 6;
    int lane = threadIdx.x & 63;
    if (gw >= B * S) return;
    const ushort4 r4v = *(const ushort4*)(enc_out + (size_t)gw * 256 + lane * 4);
    const f32x4 a4 = *(const f32x4*)(aw + 256 + lane * 4);
    float s = b2f(r4v.x) * a4[0] + b2f(r4v.y) * a4[1] + b2f(r4v.z) * a4[2] + b2f(r4v.w) * a4[3];
    #pragma unroll
    for (int off = 1; off < 64; off <<= 1) s += __shfl_xor(s, off);
    if (lane == 0) enc_score[gw] = s + ab[0];
}

__global__ void attn_kernel(const float* __restrict__ h, const __hip_bfloat16* __restrict__ enc_out,
                            const float* __restrict__ enc_score, const float* __restrict__ aw,
                            __hip_bfloat16* __restrict__ decA) {
    int b = (blockIdx.x * 256 + threadIdx.x) >> 6;
    int lane = threadIdx.x & 63;
    if (b >= B) return;
    const f32x4 h4 = *(const f32x4*)(h + (size_t)b * 256 + lane * 4);
    const f32x4 a4 = *(const f32x4*)(aw + lane * 4);
    float s = h4[0] * a4[0] + h4[1] * a4[1] + h4[2] * a4[2] + h4[3] * a4[3];
    #pragma unroll
    for (int off = 1; off < 64; off <<= 1) s += __shfl_xor(s, off);
    float sc[S], mx = -1e30f;
    #pragma unroll
    for (int t = 0; t < S; ++t) { sc[t] = s + enc_score[b * S + t]; mx = fmaxf(mx, sc[t]); }
    float sum = 0.0f;
    #pragma unroll
    for (int t = 0; t < S; ++t) { sc[t] = expf(sc[t] - mx); sum += sc[t]; }
    float inv = 1.0f / sum;
    float ctx[4] = {0.f, 0.f, 0.f, 0.f};
    #pragma unroll
    for (int t = 0; t < S; ++t) {
        const ushort4 e4 = *(const ushort4*)(enc_out + ((size_t)b * S + t) * 256 + lane * 4);
        float w = sc[t] * inv;
        ctx[0] += w * b2f(e4.x); ctx[1] += w * b2f(e4.y);
        ctx[2] += w * b2f(e4.z); ctx[3] += w * b2f(e4.w);
    }
    ushort4 o4;
    o4.x = f2bu(ctx[0]);
    o4.y = f2bu(ctx[1]);
    o4.z = f2bu(ctx[2]);
    o4.w = f2bu(ctx[3]);
    *(ushort4*)(decA + (size_t)b * 512 + lane * 4) = o4;
}

// ---------------------------------------------------------------------------
#define CDIV(a, b) (((a) + (b) - 1) / (b))

extern "C" void kernel_launch(void* const* d_in, const int* in_sizes, int n_in,
                              void* d_out, int out_size, void* d_ws, size_t ws_size,
                              hipStream_t stream) {
    const int*   text    = (const int*)  d_in[0];
    const float* surp    = (const float*)d_in[1];
    const float* emb     = (const float*)d_in[2];
    const float* sw      = (const float*)d_in[3];
    const float* sb      = (const float*)d_in[4];
    const float* ew_ih   = (const float*)d_in[5];
    const float* ew_hh   = (const float*)d_in[6];
    const float* eb_ih   = (const float*)d_in[7];
    const float* eb_hh   = (const float*)d_in[8];
    const float* aw      = (const float*)d_in[9];
    const float* ab      = (const float*)d_in[10];
    const float* dw_ih   = (const float*)d_in[11];
    const float* dw_hh   = (const float*)d_in[12];
    const float* db_ih   = (const float*)d_in[13];
    const float* db_hh   = (const float*)d_in[14];
    const float* f1w     = (const float*)d_in[15];
    const float* f1b     = (const float*)d_in[16];
    const float* f2w     = (const float*)d_in[17];
    const float* f2b     = (const float*)d_in[18];
    const float* init_in = (const float*)d_in[19];
    float* out = (float*)d_out;

    char* p = (char*)d_ws;
    auto alloc = [&](size_t bytes) {
        void* r = (void*)p;
        p += (bytes + 255) & ~(size_t)255;
        return r;
    };
    __hip_bfloat16* Wenc      = (__hip_bfloat16*)alloc((size_t)NG * 384 * 2);
    __hip_bfloat16* Wdec      = (__hip_bfloat16*)alloc((size_t)NG * 512 * 2);
    __hip_bfloat16* W1        = (__hip_bfloat16*)alloc((size_t)NG * 3328 * 2);
    __hip_bfloat16* W2        = (__hip_bfloat16*)alloc((size_t)MELP * 1024 * 2);
    float*          f2bp      = (float*)alloc((size_t)MELP * 4);
    float*          be        = (float*)alloc((size_t)NG * 4);
    float*          bd        = (float*)alloc((size_t)NG * 4);
    __hip_bfloat16* xall      = (__hip_bfloat16*)alloc((size_t)S * B * 384 * 2);
    __hip_bfloat16* enc_out   = (__hip_bfloat16*)alloc((size_t)B * S * 256 * 2);
    float*          enc_score = (float*)alloc((size_t)B * S * 4);
    float*          c_buf     = (float*)alloc((size_t)B * 256 * 4);
    float*          h_buf     = (float*)alloc((size_t)B * 256 * 4);
    __hip_bfloat16* decA      = (__hip_bfloat16*)alloc((size_t)B * 512 * 2);
    __hip_bfloat16* dec_out   = (__hip_bfloat16*)alloc((size_t)B * 3328 * 2);
    __hip_bfloat16* hfc       = (__hip_bfloat16*)alloc((size_t)B * 1024 * 2);
    (void)ws_size; (void)in_sizes; (void)n_in; (void)out_size;

    // --- weight prep (gate-permuted for the fused recurrent GEMM) ---
    pack_enc_w<<<CDIV(NG * 384, 256), 256, 0, stream>>>(ew_ih, ew_hh, Wenc);
    pack_dec_w<<<CDIV(NG * 512, 256), 256, 0, stream>>>(dw_ih, dw_hh, Wdec);
    conv_bf16<<<CDIV(NG * 3328, 256), 256, 0, stream>>>(f1w, W1, (long long)NG * 3328);
    pack_w2<<<CDIV(MELP * 1024 / 8, 256), 256, 0, stream>>>(
        f2w, W2, (long long)MEL * 1024, (long long)MELP * 1024);
    pad_bias_f32<<<CDIV(MELP, 256), 256, 0, stream>>>(f2b, f2bp, MELP, MEL);
    bias_prep<<<CDIV(NG, 256), 256, 0, stream>>>(eb_ih, eb_hh, db_ih, db_hh, dw_ih, init_in, be, bd);

    // --- inputs ---
    embed_x<<<CDIV(B * S * 32, 256), 256, 0, stream>>>(text, surp, emb, sw, sb, xall);
    init_zero<<<CDIV(B * 256, 256), 256, 0, stream>>>(c_buf, xall);

    // --- encoder: 13 fused GEMM+cell steps (512 blocks each) ---
    for (int t = 0; t < S; ++t) {
        __hip_bfloat16* hb1; int s1;
        if (t < S - 1) { hb1 = xall + ((size_t)(t + 1) * B * 384) + 128; s1 = 384; }
        else           { hb1 = decA + 256; s1 = 512; }
        float* hf = (t == S - 1) ? h_buf : (float*)nullptr;
        gemm_lstm<<<512, 256, 0, stream>>>(
            xall + (size_t)t * B * 384, Wenc, be, c_buf, hf,
            hb1, s1, enc_out + (size_t)t * 256, S * 256, 384);
    }

    // --- attention scores over encoder outputs ---
    enc_score_kernel<<<CDIV(B * S * 64, 256), 256, 0, stream>>>(enc_out, aw, ab, enc_score);

    // --- decoder: 13 steps (attn -> fused GEMM+cell) ---
    for (int t = 0; t < S; ++t) {
        attn_kernel<<<CDIV(B * 64, 256), 256, 0, stream>>>(h_buf, enc_out, enc_score, aw, decA);
        gemm_lstm<<<512, 256, 0, stream>>>(
            decA, Wdec, bd, c_buf, h_buf,
            decA + 256, 512, dec_out + (size_t)t * 256, 3328, 512);
    }

    // --- FC1: relu(dec_out @ f1w.T + f1b) -> bf16 hfc ---
    gemm2<<<(NG / 64) * (B / 128), 256, 0, stream>>>(
        dec_out, W1, f1b, (float*)nullptr, hfc, NG, 3328, NG, 1, NG / 64);

    // --- FC2: 256x256 counted-vmcnt kernel -> out (fp32) ---
    gemm256<<<(MELP / 256) * (B / 256), 512, 0, stream>>>(
        hfc, W2, f2bp, out, MEL, 1024, MEL, MELP / 256);
}

// Round 7
// 717.417 us; speedup vs baseline: 1.5759x; 1.0968x over previous
//
#include <hip/hip_runtime.h>
#include <hip/hip_bf16.h>
#include <stdint.h>
#include <stddef.h>

#define B 4096
#define S 13
#define NG 1024     // 4*HE == 4*HD
#define MEL 20000   // 80*250
#define MELP 20224  // padded to multiple of 256 (79 col-tiles for gemm256)

typedef __attribute__((ext_vector_type(8))) short bf16x8;
typedef __attribute__((ext_vector_type(4))) float f32x4;

__device__ __forceinline__ void g2l16(void* lds, const void* g) {
    __builtin_amdgcn_global_load_lds(
        (const __attribute__((address_space(1))) void*)g,
        (__attribute__((address_space(3))) void*)lds, 16, 0, 0);
}

__device__ __forceinline__ float sigm(float x) { return 1.0f / (1.0f + expf(-x)); }
__device__ __forceinline__ float b2f(unsigned short u) {
    union { float f; unsigned int i; } x; x.i = ((unsigned)u) << 16; return x.f;
}
__device__ __forceinline__ unsigned short f2bu(float f) {
    __hip_bfloat16 h = __float2bfloat16(f);
    return *reinterpret_cast<unsigned short*>(&h);
}

// Block swizzle: XCD-bijective (nwg%8==0) + grouped rows (G=4).
__device__ __forceinline__ void swz_decode(int wg, int nwg, int nx, int& bx, int& by) {
    const int cpx = nwg >> 3;
    wg = (wg & 7) * cpx + (wg >> 3);
    const int gsz = nx * 4;
    const int grp = wg / gsz, rem = wg % gsz;
    by = grp * 4 + (rem & 3);
    bx = rem >> 2;
}

#define BAR() do { asm volatile("" ::: "memory"); \
    __builtin_amdgcn_s_barrier(); \
    __builtin_amdgcn_sched_barrier(0); } while (0)

// ---------------------------------------------------------------------------
// Shared 128x64 counted-vmcnt pipeline pieces (3-buffer rotation, BK=32):
//   per tile: 3 g2l16/thread (2 A rows + 1 B row), slot-XOR swizzled source,
//   linear LDS dest; reads use matching XOR -> conflict-free ds_read_b128.
//   One barrier per tile; vmcnt(3) = exactly one tile left in flight.
// ---------------------------------------------------------------------------
#define P_DECL() \
    __shared__ __hip_bfloat16 As3[3][128 * 32]; \
    __shared__ __hip_bfloat16 Bs3[3][64 * 32]; \
    const int tid  = threadIdx.x; \
    const int lane = tid & 63; \
    const int wv   = tid >> 6; \
    const int l16  = lane & 15; \
    const int sr   = tid >> 2; \
    const int sc   = (((tid & 3) ^ ((tid >> 3) & 3)) << 3); \
    const int sl   = (((lane >> 4) ^ ((l16 >> 1) & 3)) << 3)

#define STG3(buf, k0) do { \
    g2l16(&As3[buf][sr * 32 + (tid & 3) * 8],         Ag + (size_t)sr * K + (k0) + sc); \
    g2l16(&As3[buf][(sr + 64) * 32 + (tid & 3) * 8],  Ag + (size_t)(sr + 64) * K + (k0) + sc); \
    g2l16(&Bs3[buf][sr * 32 + (tid & 3) * 8],         Wg + (size_t)sr * K + (k0) + sc); } while (0)

#define TILE3(cur, stg, k2, DO_STG) do { \
    const __hip_bfloat16* Ab = As3[cur]; \
    const __hip_bfloat16* Bb = Bs3[cur]; \
    bf16x8 af[2], bfr[4]; \
    _Pragma("unroll") for (int m = 0; m < 2; ++m) \
        af[m] = *(const bf16x8*)(Ab + (wv * 32 + m * 16 + l16) * 32 + sl); \
    _Pragma("unroll") for (int n = 0; n < 4; ++n) \
        bfr[n] = *(const bf16x8*)(Bb + (n * 16 + l16) * 32 + sl); \
    if (DO_STG) STG3(stg, k2); \
    __builtin_amdgcn_s_setprio(1); \
    _Pragma("unroll") for (int m = 0; m < 2; ++m) \
        _Pragma("unroll") for (int n = 0; n < 4; ++n) \
            acc[m][n] = __builtin_amdgcn_mfma_f32_16x16x32_bf16(af[m], bfr[n], acc[m][n], 0, 0, 0); \
    __builtin_amdgcn_s_setprio(0); \
} while (0)

#define PIPELINE(K) do { \
    const int nk = (K) >> 5; \
    STG3(0, 0); \
    STG3(1, 32); \
    asm volatile("s_waitcnt vmcnt(3)" ::: "memory"); \
    BAR(); \
    int cur = 0; \
    for (int t = 0; t < nk - 2; ++t) { \
        const int stg = cur >= 1 ? cur - 1 : 2; \
        TILE3(cur, stg, (t + 2) << 5, true); \
        asm volatile("s_waitcnt vmcnt(3)" ::: "memory"); \
        BAR(); \
        cur = cur == 2 ? 0 : cur + 1; \
    } \
    TILE3(cur, 0, 0, false); \
    asm volatile("s_waitcnt vmcnt(0)" ::: "memory"); \
    BAR(); \
    cur = cur == 2 ? 0 : cur + 1; \
    TILE3(cur, 0, 0, false); \
} while (0)

// ---------------------------------------------------------------------------
// Generic 128x64 counted-vmcnt GEMM (FC1): C = A @ W^T + bias, relu, bf16/f32
// ---------------------------------------------------------------------------
__global__ __launch_bounds__(256, 2) void gemm3(
    const __hip_bfloat16* __restrict__ A,
    const __hip_bfloat16* __restrict__ W,
    const float* __restrict__ bias,
    float* __restrict__ Cf,
    __hip_bfloat16* __restrict__ Cbf,
    int N, int K, int ldc, int relu, int nx)
{
    P_DECL();
    int bx, by;
    swz_decode(blockIdx.x, gridDim.x, nx, bx, by);
    const int brow = by * 128, bcol = bx * 64;
    const __hip_bfloat16* Ag = A + (size_t)brow * K;
    const __hip_bfloat16* Wg = W + (size_t)bcol * K;
    f32x4 acc[2][4] = {};

    PIPELINE(K);

    const int r4 = (lane >> 4) * 4;
    #pragma unroll
    for (int m = 0; m < 2; ++m) {
        #pragma unroll
        for (int n = 0; n < 4; ++n) {
            const int col = bcol + n * 16 + l16;
            if (col >= N) continue;
            const float bv = bias ? bias[col] : 0.0f;
            #pragma unroll
            for (int r = 0; r < 4; ++r) {
                const int row = brow + wv * 32 + m * 16 + r4 + r;
                float v = acc[m][n][r] + bv;
                if (relu) v = v > 0.0f ? v : 0.0f;
                if (Cf)  Cf[(size_t)row * ldc + col] = v;
                if (Cbf) Cbf[(size_t)row * ldc + col] = __float2bfloat16(v);
            }
        }
    }
}

// ---------------------------------------------------------------------------
// Fused GEMM + LSTM cell on the counted-vmcnt pipeline. Weights gate-permuted:
//   n = g*256+u -> n' = (u>>4)*64 + g*16 + (u&15)
// ---------------------------------------------------------------------------
__global__ __launch_bounds__(256, 2) void gemm_lstm3(
    const __hip_bfloat16* __restrict__ A,
    const __hip_bfloat16* __restrict__ W,
    const float* __restrict__ bias,
    float* __restrict__ c,
    float* __restrict__ hf,
    __hip_bfloat16* __restrict__ hb1, int s1,
    __hip_bfloat16* __restrict__ hb2, int s2,
    int K)
{
    P_DECL();
    int bx, by;
    swz_decode(blockIdx.x, gridDim.x, 16, bx, by);
    const int brow = by * 128, bcol = bx * 64;
    const __hip_bfloat16* Ag = A + (size_t)brow * K;
    const __hip_bfloat16* Wg = W + (size_t)bcol * K;
    f32x4 acc[2][4] = {};

    PIPELINE(K);

    const int r4 = (lane >> 4) * 4;
    const int unit = bx * 16 + l16;
    const float b0 = bias[bcol + l16];
    const float b1 = bias[bcol + 16 + l16];
    const float b2 = bias[bcol + 32 + l16];
    const float b3 = bias[bcol + 48 + l16];
    #pragma unroll
    for (int m = 0; m < 2; ++m) {
        #pragma unroll
        for (int r = 0; r < 4; ++r) {
            const int row = brow + wv * 32 + m * 16 + r4 + r;
            const float gi = acc[m][0][r] + b0;
            const float gf = acc[m][1][r] + b1;
            const float gg = acc[m][2][r] + b2;
            const float go = acc[m][3][r] + b3;
            const size_t ci = (size_t)row * 256 + unit;
            const float c2 = sigm(gf) * c[ci] + sigm(gi) * tanhf(gg);
            const float h2 = sigm(go) * tanhf(c2);
            c[ci] = c2;
            if (hf) hf[ci] = h2;
            const __hip_bfloat16 hb = __float2bfloat16(h2);
            hb1[(size_t)row * s1 + unit] = hb;
            if (hb2) hb2[(size_t)row * s2 + unit] = hb;
        }
    }
}

// ---------------------------------------------------------------------------
// 256x256 multi-phase counted-vmcnt GEMM (FC2) — unchanged from R6.
// ---------------------------------------------------------------------------
__global__ __launch_bounds__(512, 2) void gemm256(
    const __hip_bfloat16* __restrict__ A,
    const __hip_bfloat16* __restrict__ W,
    const float* __restrict__ bias,
    float* __restrict__ Cf,
    int N, int K, int ldc, int nx)
{
    __shared__ __hip_bfloat16 As[3][256 * 32];
    __shared__ __hip_bfloat16 Bs[3][256 * 32];
    const int tid  = threadIdx.x;
    const int lane = tid & 63;
    const int wv = tid >> 6, wr = wv >> 2, wc = wv & 3;
    const int l16 = lane & 15;
    int bx, by;
    {
        int wg = blockIdx.x; const int nwg = gridDim.x;
        const int cpx = nwg >> 3;
        wg = (wg & 7) * cpx + (wg >> 3);
        const int gsz = nx * 2;
        const int grp = wg / gsz, rem = wg % gsz;
        by = grp * 2 + (rem & 1);
        bx = rem >> 1;
    }
    const int brow = by * 256, bcol = bx * 256;
    const __hip_bfloat16* Ag = A + (size_t)brow * K;
    const __hip_bfloat16* Wg = W + (size_t)bcol * K;
    const int sr = tid >> 2;
    const int sc = (((tid & 3) ^ ((tid >> 3) & 3)) << 3);
    const int sd = tid * 8;
    const int sl = (((lane >> 4) ^ ((l16 >> 1) & 3)) << 3);
    f32x4 acc[8][4] = {};
    const int nk = K >> 5;

    #define STG_A(buf, k0) do { \
        g2l16(&As[buf][sd],        Ag + (size_t)sr * K + (k0) + sc);         \
        g2l16(&As[buf][4096 + sd], Ag + (size_t)(sr + 128) * K + (k0) + sc); } while (0)
    #define STG_B(buf, k0) do { \
        g2l16(&Bs[buf][sd],        Wg + (size_t)sr * K + (k0) + sc);         \
        g2l16(&Bs[buf][4096 + sd], Wg + (size_t)(sr + 128) * K + (k0) + sc); } while (0)

    #define TILE(cur, stg, k2, DO_STG) do {                                    \
        const __hip_bfloat16* Ab = As[cur];                                    \
        const __hip_bfloat16* Bb = Bs[cur];                                    \
        bf16x8 bfr[4], af[4];                                                  \
        _Pragma("unroll") for (int n = 0; n < 4; ++n)                          \
            bfr[n] = *(const bf16x8*)(Bb + (wc * 64 + n * 16 + l16) * 32 + sl);\
        _Pragma("unroll") for (int m = 0; m < 4; ++m)                          \
            af[m] = *(const bf16x8*)(Ab + (wr * 128 + m * 16 + l16) * 32 + sl);\
        if (DO_STG) STG_A(stg, k2);                                            \
        BAR();                                                                 \
        __builtin_amdgcn_s_setprio(1);                                         \
        _Pragma("unroll") for (int m = 0; m < 4; ++m)                          \
            _Pragma("unroll") for (int n = 0; n < 4; ++n)                      \
                acc[m][n] = __builtin_amdgcn_mfma_f32_16x16x32_bf16(           \
                    af[m], bfr[n], acc[m][n], 0, 0, 0);                        \
        __builtin_amdgcn_s_setprio(0);                                         \
        BAR();                                                                 \
        _Pragma("unroll") for (int m = 0; m < 4; ++m)                          \
            af[m] = *(const bf16x8*)(Ab + (wr * 128 + (m + 4) * 16 + l16) * 32 + sl); \
        if (DO_STG) STG_B(stg, k2);                                            \
        BAR();                                                                 \
        __builtin_amdgcn_s_setprio(1);                                         \
        _Pragma("unroll") for (int m = 0; m < 4; ++m)                          \
            _Pragma("unroll") for (int n = 0; n < 4; ++n)                      \
                acc[m + 4][n] = __builtin_amdgcn_mfma_f32_16x16x32_bf16(       \
                    af[m], bfr[n], acc[m + 4][n], 0, 0, 0);                    \
        __builtin_amdgcn_s_setprio(0);                                         \
    } while (0)

    STG_A(0, 0);  STG_B(0, 0);
    STG_A(1, 32); STG_B(1, 32);
    asm volatile("s_waitcnt vmcnt(4)" ::: "memory");
    BAR();
    int cur = 0;
    for (int t = 0; t < nk - 2; ++t) {
        const int stg = cur >= 1 ? cur - 1 : 2;
        TILE(cur, stg, (t + 2) << 5, true);
        asm volatile("s_waitcnt vmcnt(4)" ::: "memory");
        BAR();
        cur = cur == 2 ? 0 : cur + 1;
    }
    TILE(cur, 0, 0, false);
    asm volatile("s_waitcnt vmcnt(0)" ::: "memory");
    BAR();
    cur = cur == 2 ? 0 : cur + 1;
    TILE(cur, 0, 0, false);

    const int r4 = (lane >> 4) * 4;
    #pragma unroll
    for (int m = 0; m < 8; ++m) {
        #pragma unroll
        for (int n = 0; n < 4; ++n) {
            const int col = bcol + wc * 64 + n * 16 + l16;
            if (col >= N) continue;
            const float bv = bias[col];
            #pragma unroll
            for (int r = 0; r < 4; ++r) {
                const int row = brow + wr * 128 + m * 16 + r4 + r;
                Cf[(size_t)row * ldc + col] = acc[m][n][r] + bv;
            }
        }
    }
}

// ---------------------------------------------------------------------------
// Weight prep / packing kernels (gate-permuted layouts)
// ---------------------------------------------------------------------------
__device__ __forceinline__ int unperm(int np) {
    const int u = ((np >> 6) << 4) + (np & 15);
    const int g = (np >> 4) & 3;
    return g * 256 + u;
}

__global__ void pack_enc_w(const float* __restrict__ ew_ih, const float* __restrict__ ew_hh,
                           __hip_bfloat16* __restrict__ out) {
    int idx = blockIdx.x * 256 + threadIdx.x;
    if (idx >= NG * 384) return;
    int np = idx / 384, k = idx % 384;
    int n = unperm(np);
    float v = (k < 128) ? ew_ih[n * 128 + k] : ew_hh[n * 256 + (k - 128)];
    out[idx] = __float2bfloat16(v);
}

__global__ void pack_dec_w(const float* __restrict__ dw_ih, const float* __restrict__ dw_hh,
                           __hip_bfloat16* __restrict__ out) {
    int idx = blockIdx.x * 256 + threadIdx.x;
    if (idx >= NG * 512) return;
    int np = idx / 512, k = idx % 512;
    int n = unperm(np);
    float v = (k < 256) ? dw_ih[n * 384 + 128 + k] : dw_hh[n * 256 + (k - 256)];
    out[idx] = __float2bfloat16(v);
}

__global__ void conv_bf16(const float* __restrict__ in, __hip_bfloat16* __restrict__ out,
                          long long n) {
    long long idx = (long long)blockIdx.x * 256 + threadIdx.x;
    if (idx >= n) return;
    out[idx] = __float2bfloat16(in[idx]);
}

__global__ void pack_w2(const float* __restrict__ in, __hip_bfloat16* __restrict__ out,
                        long long n_in, long long n_out) {
    long long i8 = ((long long)blockIdx.x * 256 + threadIdx.x) * 8;
    if (i8 >= n_out) return;
    union { bf16x8 v; __hip_bfloat16 e[8]; } u;
    if (i8 < n_in) {
        f32x4 a = *(const f32x4*)(in + i8);
        f32x4 b = *(const f32x4*)(in + i8 + 4);
        #pragma unroll
        for (int j = 0; j < 4; ++j) { u.e[j] = __float2bfloat16(a[j]); u.e[4 + j] = __float2bfloat16(b[j]); }
    } else {
        #pragma unroll
        for (int j = 0; j < 8; ++j) u.e[j] = __float2bfloat16(0.0f);
    }
    *(bf16x8*)(out + i8) = u.v;
}

__global__ void pad_bias_f32(const float* __restrict__ in, float* __restrict__ out,
                             int n_out, int n_in) {
    int idx = blockIdx.x * 256 + threadIdx.x;
    if (idx >= n_out) return;
    out[idx] = (idx < n_in) ? in[idx] : 0.0f;
}

__global__ void bias_prep(const float* __restrict__ eb_ih, const float* __restrict__ eb_hh,
                          const float* __restrict__ db_ih, const float* __restrict__ db_hh,
                          const float* __restrict__ dw_ih, const float* __restrict__ init_in,
                          float* __restrict__ be, float* __restrict__ bd) {
    int np = blockIdx.x * 256 + threadIdx.x;
    if (np >= NG) return;
    int n = unperm(np);
    be[np] = eb_ih[n] + eb_hh[n];
    float s = db_ih[n] + db_hh[n];
    for (int k = 0; k < 128; ++k) s += dw_ih[n * 384 + k] * init_in[k];
    bd[np] = s;
}

__global__ void embed_x(const int* __restrict__ text, const float* __restrict__ surp,
                        const float* __restrict__ emb, const float* __restrict__ sw,
                        const float* __restrict__ sb, __hip_bfloat16* __restrict__ xall) {
    int idx = blockIdx.x * 256 + threadIdx.x;
    if (idx >= B * S * 32) return;
    int jj = (idx & 31) * 4;
    int rest = idx >> 5;
    int b = rest % B;
    int s = rest / B;
    const float sp = surp[b * S + s];
    const f32x4 e4 = *(const f32x4*)(emb + (size_t)text[b * S + s] * 128 + jj);
    const f32x4 w4 = *(const f32x4*)(sw + jj);
    const f32x4 b4 = *(const f32x4*)(sb + jj);
    __hip_bfloat16* dst = xall + ((size_t)s * B + b) * 384 + jj;
    #pragma unroll
    for (int i = 0; i < 4; ++i) dst[i] = __float2bfloat16(e4[i] + sp * w4[i] + b4[i]);
}

__global__ void init_zero(float* __restrict__ c, __hip_bfloat16* __restrict__ x0h) {
    int idx = blockIdx.x * 256 + threadIdx.x;
    if (idx >= B * 256) return;
    c[idx] = 0.0f;
    int b = idx >> 8, jj = idx & 255;
    x0h[(size_t)b * 384 + 128 + jj] = __float2bfloat16(0.0f);
}

__global__ void enc_score_kernel(const __hip_bfloat16* __restrict__ enc_out,
                                 const float* __restrict__ aw, const float* __restrict__ ab,
                                 float* __restrict__ enc_score) {
    int gw = (blockIdx.x * 256 + threadIdx.x) >> 6;
    int lane = threadIdx.x & 63;
    if (gw >= B * S) return;
    const ushort4 r4v = *(const ushort4*)(enc_out + (size_t)gw * 256 + lane * 4);
    const f32x4 a4 = *(const f32x4*)(aw + 256 + lane * 4);
    float s = b2f(r4v.x) * a4[0] + b2f(r4v.y) * a4[1] + b2f(r4v.z) * a4[2] + b2f(r4v.w) * a4[3];
    #pragma unroll
    for (int off = 1; off < 64; off <<= 1) s += __shfl_xor(s, off);
    if (lane == 0) enc_score[gw] = s + ab[0];
}

__global__ void attn_kernel(const float* __restrict__ h, const __hip_bfloat16* __restrict__ enc_out,
                            const float* __restrict__ enc_score, const float* __restrict__ aw,
                            __hip_bfloat16* __restrict__ decA) {
    int b = (blockIdx.x * 256 + threadIdx.x) >> 6;
    int lane = threadIdx.x & 63;
    if (b >= B) return;
    const f32x4 h4 = *(const f32x4*)(h + (size_t)b * 256 + lane * 4);
    const f32x4 a4 = *(const f32x4*)(aw + lane * 4);
    float s = h4[0] * a4[0] + h4[1] * a4[1] + h4[2] * a4[2] + h4[3] * a4[3];
    #pragma unroll
    for (int off = 1; off < 64; off <<= 1) s += __shfl_xor(s, off);
    float sc[S], mx = -1e30f;
    #pragma unroll
    for (int t = 0; t < S; ++t) { sc[t] = s + enc_score[b * S + t]; mx = fmaxf(mx, sc[t]); }
    float sum = 0.0f;
    #pragma unroll
    for (int t = 0; t < S; ++t) { sc[t] = expf(sc[t] - mx); sum += sc[t]; }
    float inv = 1.0f / sum;
    float ctx[4] = {0.f, 0.f, 0.f, 0.f};
    #pragma unroll
    for (int t = 0; t < S; ++t) {
        const ushort4 e4 = *(const ushort4*)(enc_out + ((size_t)b * S + t) * 256 + lane * 4);
        float w = sc[t] * inv;
        ctx[0] += w * b2f(e4.x); ctx[1] += w * b2f(e4.y);
        ctx[2] += w * b2f(e4.z); ctx[3] += w * b2f(e4.w);
    }
    ushort4 o4;
    o4.x = f2bu(ctx[0]);
    o4.y = f2bu(ctx[1]);
    o4.z = f2bu(ctx[2]);
    o4.w = f2bu(ctx[3]);
    *(ushort4*)(decA + (size_t)b * 512 + lane * 4) = o4;
}

// ---------------------------------------------------------------------------
#define CDIV(a, b) (((a) + (b) - 1) / (b))

extern "C" void kernel_launch(void* const* d_in, const int* in_sizes, int n_in,
                              void* d_out, int out_size, void* d_ws, size_t ws_size,
                              hipStream_t stream) {
    const int*   text    = (const int*)  d_in[0];
    const float* surp    = (const float*)d_in[1];
    const float* emb     = (const float*)d_in[2];
    const float* sw      = (const float*)d_in[3];
    const float* sb      = (const float*)d_in[4];
    const float* ew_ih   = (const float*)d_in[5];
    const float* ew_hh   = (const float*)d_in[6];
    const float* eb_ih   = (const float*)d_in[7];
    const float* eb_hh   = (const float*)d_in[8];
    const float* aw      = (const float*)d_in[9];
    const float* ab      = (const float*)d_in[10];
    const float* dw_ih   = (const float*)d_in[11];
    const float* dw_hh   = (const float*)d_in[12];
    const float* db_ih   = (const float*)d_in[13];
    const float* db_hh   = (const float*)d_in[14];
    const float* f1w     = (const float*)d_in[15];
    const float* f1b     = (const float*)d_in[16];
    const float* f2w     = (const float*)d_in[17];
    const float* f2b     = (const float*)d_in[18];
    const float* init_in = (const float*)d_in[19];
    float* out = (float*)d_out;

    char* p = (char*)d_ws;
    auto alloc = [&](size_t bytes) {
        void* r = (void*)p;
        p += (bytes + 255) & ~(size_t)255;
        return r;
    };
    __hip_bfloat16* Wenc      = (__hip_bfloat16*)alloc((size_t)NG * 384 * 2);
    __hip_bfloat16* Wdec      = (__hip_bfloat16*)alloc((size_t)NG * 512 * 2);
    __hip_bfloat16* W1        = (__hip_bfloat16*)alloc((size_t)NG * 3328 * 2);
    __hip_bfloat16* W2        = (__hip_bfloat16*)alloc((size_t)MELP * 1024 * 2);
    float*          f2bp      = (float*)alloc((size_t)MELP * 4);
    float*          be        = (float*)alloc((size_t)NG * 4);
    float*          bd        = (float*)alloc((size_t)NG * 4);
    __hip_bfloat16* xall      = (__hip_bfloat16*)alloc((size_t)S * B * 384 * 2);
    __hip_bfloat16* enc_out   = (__hip_bfloat16*)alloc((size_t)B * S * 256 * 2);
    float*          enc_score = (float*)alloc((size_t)B * S * 4);
    float*          c_buf     = (float*)alloc((size_t)B * 256 * 4);
    float*          h_buf     = (float*)alloc((size_t)B * 256 * 4);
    __hip_bfloat16* decA      = (__hip_bfloat16*)alloc((size_t)B * 512 * 2);
    __hip_bfloat16* dec_out   = (__hip_bfloat16*)alloc((size_t)B * 3328 * 2);
    __hip_bfloat16* hfc       = (__hip_bfloat16*)alloc((size_t)B * 1024 * 2);
    (void)ws_size; (void)in_sizes; (void)n_in; (void)out_size;

    // --- weight prep (gate-permuted for the fused recurrent GEMM) ---
    pack_enc_w<<<CDIV(NG * 384, 256), 256, 0, stream>>>(ew_ih, ew_hh, Wenc);
    pack_dec_w<<<CDIV(NG * 512, 256), 256, 0, stream>>>(dw_ih, dw_hh, Wdec);
    conv_bf16<<<CDIV(NG * 3328, 256), 256, 0, stream>>>(f1w, W1, (long long)NG * 3328);
    pack_w2<<<CDIV(MELP * 1024 / 8, 256), 256, 0, stream>>>(
        f2w, W2, (long long)MEL * 1024, (long long)MELP * 1024);
    pad_bias_f32<<<CDIV(MELP, 256), 256, 0, stream>>>(f2b, f2bp, MELP, MEL);
    bias_prep<<<CDIV(NG, 256), 256, 0, stream>>>(eb_ih, eb_hh, db_ih, db_hh, dw_ih, init_in, be, bd);

    // --- inputs ---
    embed_x<<<CDIV(B * S * 32, 256), 256, 0, stream>>>(text, surp, emb, sw, sb, xall);
    init_zero<<<CDIV(B * 256, 256), 256, 0, stream>>>(c_buf, xall);

    // --- encoder: 13 fused GEMM+cell steps (512 blocks each) ---
    for (int t = 0; t < S; ++t) {
        __hip_bfloat16* hb1; int s1;
        if (t < S - 1) { hb1 = xall + ((size_t)(t + 1) * B * 384) + 128; s1 = 384; }
        else           { hb1 = decA + 256; s1 = 512; }
        float* hf = (t == S - 1) ? h_buf : (float*)nullptr;
        gemm_lstm3<<<512, 256, 0, stream>>>(
            xall + (size_t)t * B * 384, Wenc, be, c_buf, hf,
            hb1, s1, enc_out + (size_t)t * 256, S * 256, 384);
    }

    // --- attention scores over encoder outputs ---
    enc_score_kernel<<<CDIV(B * S * 64, 256), 256, 0, stream>>>(enc_out, aw, ab, enc_score);

    // --- decoder: 13 steps (attn -> fused GEMM+cell) ---
    for (int t = 0; t < S; ++t) {
        attn_kernel<<<CDIV(B * 64, 256), 256, 0, stream>>>(h_buf, enc_out, enc_score, aw, decA);
        gemm_lstm3<<<512, 256, 0, stream>>>(
            decA, Wdec, bd, c_buf, h_buf,
            decA + 256, 512, dec_out + (size_t)t * 256, 3328, 512);
    }

    // --- FC1: relu(dec_out @ f1w.T + f1b) -> bf16 hfc ---
    gemm3<<<(NG / 64) * (B / 128), 256, 0, stream>>>(
        dec_out, W1, f1b, (float*)nullptr, hfc, NG, 3328, NG, 1, NG / 64);

    // --- FC2: 256x256 counted-vmcnt kernel -> out (fp32) ---
    gemm256<<<(MELP / 256) * (B / 256), 512, 0, stream>>>(
        hfc, W2, f2bp, out, MEL, 1024, MEL, MELP / 256);
}